// Round 1
// baseline (545.653 us; speedup 1.0000x reference)
//
#include <hip/hip_runtime.h>
#include <math.h>

#define MM 16384
#define NN 8192
#define DD 128

#define L2E  1.4426950408889634f
#define COEF 0.15915494309189535f   // 1/(2*pi)

// ---------------------------------------------------------------------------
// Pre-pass: xc[m] = -0.5*|x_m|^2*log2e ; mc[n] = (ln w_n - 0.5*|mu_n|^2)*log2e
// ---------------------------------------------------------------------------
__global__ __launch_bounds__(256) void gmm_prep(
    const float* __restrict__ x, const float* __restrict__ means,
    const float* __restrict__ w, float* __restrict__ xc, float* __restrict__ mc)
{
    int tid = blockIdx.x * 256 + threadIdx.x;
    if (tid < MM) {
        const float4* row = (const float4*)(x + (size_t)tid * DD);
        float ss = 0.f;
        #pragma unroll
        for (int i = 0; i < DD / 4; ++i) {
            float4 v = row[i];
            ss = fmaf(v.x, v.x, fmaf(v.y, v.y, fmaf(v.z, v.z, fmaf(v.w, v.w, ss))));
        }
        xc[tid] = -0.5f * ss * L2E;
    } else if (tid < MM + NN) {
        int n = tid - MM;
        const float4* row = (const float4*)(means + (size_t)n * DD);
        float ss = 0.f;
        #pragma unroll
        for (int i = 0; i < DD / 4; ++i) {
            float4 v = row[i];
            ss = fmaf(v.x, v.x, fmaf(v.y, v.y, fmaf(v.z, v.z, fmaf(v.w, v.w, ss))));
        }
        mc[n] = (logf(w[n]) - 0.5f * ss) * L2E;
    }
}

// ---------------------------------------------------------------------------
// Main kernel: 128x128 output tile per block, 8x8 micro-tile per thread.
// A (x tile) fully resident in LDS; B (means) double-buffered in BK=16 slices.
// LDS layouts are [k][elem] with an XOR swizzle on 8-element groups so that
// fragment reads are aligned ds_read_b128 and staging writes stay <=8-way.
// Epilogue: exp2(dot*L2E + xc + mc) accumulated per row across all N tiles.
// Grid: (M/128, 4) -> each block covers N/4 = 2048 means; 4 atomicAdds/row.
// LDS total = 64KB + 2*8KB = 80KB exactly -> 2 blocks/CU (8 waves/CU).
// ---------------------------------------------------------------------------
__global__ __launch_bounds__(256, 2) void gmm_main(
    const float* __restrict__ x, const float* __restrict__ means,
    const float* __restrict__ xc, const float* __restrict__ mc,
    float* __restrict__ out)
{
    __shared__ __align__(16) float Asm[128 * 128];     // 64 KB
    __shared__ __align__(16) float Bsm[2][16 * 128];   // 2 x 8 KB

    const int t   = threadIdx.x;
    const int tc  = t & 15;         // column-thread  (cols n = 8*tc + j)
    const int tr  = t >> 4;         // row-thread     (rows r = 8*tr + i)
    const int r0  = blockIdx.x * 128;
    const int nq0 = blockIdx.y * 2048;

    // ---- stage A tile (x[r0..r0+127][0..127]) into LDS, layout [k][swz(r)]
    {
        float4 tmp[16];
        #pragma unroll
        for (int ii = 0; ii < 16; ++ii) {
            int idx = t + ii * 256;            // 0..4095 float4s
            int r   = idx >> 5;                // 32 float4 per row
            int k0  = (idx & 31) << 2;
            tmp[ii] = *(const float4*)(x + (size_t)(r0 + r) * DD + k0);
        }
        #pragma unroll
        for (int ii = 0; ii < 16; ++ii) {
            int idx = t + ii * 256;
            int r   = idx >> 5;
            int k0  = (idx & 31) << 2;
            int rb  = r >> 3, rl = r & 7;
            float v[4] = {tmp[ii].x, tmp[ii].y, tmp[ii].z, tmp[ii].w};
            #pragma unroll
            for (int j = 0; j < 4; ++j) {
                int k = k0 + j;
                Asm[k * 128 + (((rb ^ (k & 15)) << 3) | rl)] = v[j];
            }
        }
    }

    // per-thread row constants
    float xcv[8];
    {
        float4 a = *(const float4*)(xc + r0 + tr * 8);
        float4 b = *(const float4*)(xc + r0 + tr * 8 + 4);
        xcv[0] = a.x; xcv[1] = a.y; xcv[2] = a.z; xcv[3] = a.w;
        xcv[4] = b.x; xcv[5] = b.y; xcv[6] = b.z; xcv[7] = b.w;
    }

    float rowAcc[8];
    #pragma unroll
    for (int i = 0; i < 8; ++i) rowAcc[i] = 0.f;

    for (int ntile = 0; ntile < 16; ++ntile) {
        const int nbase = nq0 + ntile * 128;

        float acc[8][8];
        #pragma unroll
        for (int i = 0; i < 8; ++i)
            #pragma unroll
            for (int j = 0; j < 8; ++j) acc[i][j] = 0.f;

        // prefetch slice 0 into registers
        float4 ld[2];
        #pragma unroll
        for (int ii = 0; ii < 2; ++ii) {
            int flat = t + ii * 256;           // 0..511 float4s
            int nl   = flat >> 2;              // 4 float4 per mean-row-slice
            int kl   = (flat & 3) << 2;
            ld[ii] = *(const float4*)(means + (size_t)(nbase + nl) * DD + kl);
        }

        for (int ks = 0; ks < 8; ++ks) {
            const int buf = ks & 1;
            // write prefetched slice into LDS[buf]
            #pragma unroll
            for (int ii = 0; ii < 2; ++ii) {
                int flat = t + ii * 256;
                int nl   = flat >> 2;
                int k0   = (flat & 3) << 2;
                int nb   = nl >> 3, nll = nl & 7;
                float v[4] = {ld[ii].x, ld[ii].y, ld[ii].z, ld[ii].w};
                #pragma unroll
                for (int j = 0; j < 4; ++j) {
                    int kl = k0 + j;
                    Bsm[buf][kl * 128 + (((nb ^ kl) << 3) | nll)] = v[j];
                }
            }
            // prefetch next slice (latency hidden behind compute below)
            if (ks < 7) {
                #pragma unroll
                for (int ii = 0; ii < 2; ++ii) {
                    int flat = t + ii * 256;
                    int nl   = flat >> 2;
                    int kl   = (flat & 3) << 2;
                    ld[ii] = *(const float4*)(means + (size_t)(nbase + nl) * DD
                                              + (ks + 1) * 16 + kl);
                }
            }
            __syncthreads();   // single barrier per slice (double-buffered)

            // compute 16 k-steps from LDS
            #pragma unroll
            for (int kk = 0; kk < 16; ++kk) {
                const int k = ks * 16 + kk;
                const float* ap = &Asm[k * 128 + ((tr ^ kk) << 3)];
                float4 a0 = *(const float4*)ap;
                float4 a1 = *(const float4*)(ap + 4);
                const float* bp = &Bsm[buf][kk * 128 + ((tc ^ kk) << 3)];
                float4 b0 = *(const float4*)bp;
                float4 b1 = *(const float4*)(bp + 4);
                float av[8] = {a0.x, a0.y, a0.z, a0.w, a1.x, a1.y, a1.z, a1.w};
                float bv[8] = {b0.x, b0.y, b0.z, b0.w, b1.x, b1.y, b1.z, b1.w};
                #pragma unroll
                for (int i = 0; i < 8; ++i)
                    #pragma unroll
                    for (int j = 0; j < 8; ++j)
                        acc[i][j] = fmaf(av[i], bv[j], acc[i][j]);
            }
        }

        // epilogue: exp2(dot*L2E + xc + mc), accumulate per row
        float mcv[8];
        {
            float4 a = *(const float4*)(mc + nbase + tc * 8);
            float4 b = *(const float4*)(mc + nbase + tc * 8 + 4);
            mcv[0] = a.x; mcv[1] = a.y; mcv[2] = a.z; mcv[3] = a.w;
            mcv[4] = b.x; mcv[5] = b.y; mcv[6] = b.z; mcv[7] = b.w;
        }
        #pragma unroll
        for (int i = 0; i < 8; ++i) {
            float s = 0.f;
            #pragma unroll
            for (int j = 0; j < 8; ++j) {
                float arg = fmaf(acc[i][j], L2E, xcv[i] + mcv[j]);
                s += __builtin_exp2f(arg);
            }
            rowAcc[i] += s;
        }
    }

    // reduce across the 16 column-threads (all in-wave, width 16), then atomic
    #pragma unroll
    for (int i = 0; i < 8; ++i) {
        float v = rowAcc[i];
        v += __shfl_xor(v, 1, 16);
        v += __shfl_xor(v, 2, 16);
        v += __shfl_xor(v, 4, 16);
        v += __shfl_xor(v, 8, 16);
        if (tc == 0) atomicAdd(out + r0 + tr * 8 + i, COEF * v);
    }
}

extern "C" void kernel_launch(void* const* d_in, const int* in_sizes, int n_in,
                              void* d_out, int out_size, void* d_ws, size_t ws_size,
                              hipStream_t stream) {
    const float* x     = (const float*)d_in[0];
    const float* means = (const float*)d_in[1];
    const float* w     = (const float*)d_in[2];
    float* out = (float*)d_out;
    float* xc  = (float*)d_ws;        // MM floats
    float* mc  = xc + MM;             // NN floats   (total 96 KB of ws)

    hipMemsetAsync(out, 0, MM * sizeof(float), stream);
    gmm_prep<<<(MM + NN + 255) / 256, 256, 0, stream>>>(x, means, w, xc, mc);
    gmm_main<<<dim3(MM / 128, 4), 256, 0, stream>>>(x, means, xc, mc, out);
}

// Round 2
// 233.116 us; speedup vs baseline: 2.3407x; 2.3407x over previous
//
#include <hip/hip_runtime.h>
#include <math.h>

#define MM 16384
#define NN 8192
#define DD 128

#define L2E  1.4426950408889634f
#define COEF 0.15915494309189535f   // 1/(2*pi)

// ---------------------------------------------------------------------------
// bf16 helpers (RNE), dependency-free
// ---------------------------------------------------------------------------
__device__ __forceinline__ unsigned short f2bf(float f) {
    unsigned u = __float_as_uint(f);
    u = (u + 0x7FFFu + ((u >> 16) & 1u)) >> 16;
    return (unsigned short)u;
}
__device__ __forceinline__ float bf2f(unsigned short h) {
    return __uint_as_float((unsigned)h << 16);
}

__device__ __forceinline__ void async16(short* lds, const short* g) {
    __builtin_amdgcn_global_load_lds(
        (const __attribute__((address_space(1))) unsigned int*)g,
        (__attribute__((address_space(3))) unsigned int*)lds,
        16, 0, 0);
}

typedef __attribute__((ext_vector_type(8))) short bf16x8;
typedef __attribute__((ext_vector_type(4))) float f32x4;

// ---------------------------------------------------------------------------
// Pre-pass (bf16 path): one wave per row.
//  x rows  -> Acat[m][0:128]=hi(x*L2E), [128:256]=lo, [256:384]=hi
//  mean rows -> Bcat[n][0:128]=hi(mu),  [128:256]=hi, [256:384]=lo
//  so dot(Acat_row, Bcat_row) = a_hi*b_hi + a_lo*b_hi + a_hi*b_lo ~= (x*L2E).mu
//  xc[m] = -0.5|x|^2*L2E ; mc[n] = (ln w - 0.5|mu|^2)*L2E
// ---------------------------------------------------------------------------
__global__ __launch_bounds__(256) void gmm_prep_bf16(
    const float* __restrict__ x, const float* __restrict__ means,
    const float* __restrict__ w, short* __restrict__ Acat,
    short* __restrict__ Bcat, float* __restrict__ xc, float* __restrict__ mc)
{
    const int row  = blockIdx.x * 4 + (threadIdx.x >> 6);
    const int lane = threadIdx.x & 63;
    const bool isx = row < MM;
    const int n = row - MM;

    const float* src = isx ? (x + (size_t)row * DD + lane * 2)
                           : (means + (size_t)n * DD + lane * 2);
    float2 v = *(const float2*)src;
    float ss = fmaf(v.x, v.x, v.y * v.y);

    float a0 = isx ? v.x * L2E : v.x;
    float a1 = isx ? v.y * L2E : v.y;
    unsigned short h0 = f2bf(a0), h1 = f2bf(a1);
    unsigned short l0 = f2bf(a0 - bf2f(h0)), l1 = f2bf(a1 - bf2f(h1));
    unsigned hi = ((unsigned)h1 << 16) | h0;
    unsigned lo = ((unsigned)l1 << 16) | l0;

    short* dst = (isx ? Acat + (size_t)row * 384 : Bcat + (size_t)n * 384)
                 + 2 * lane;
    *(unsigned*)(dst)       = hi;
    *(unsigned*)(dst + 128) = isx ? lo : hi;
    *(unsigned*)(dst + 256) = isx ? hi : lo;

    #pragma unroll
    for (int m = 1; m < 64; m <<= 1) ss += __shfl_xor(ss, m, 64);
    if (lane == 0) {
        if (isx) xc[row] = -0.5f * ss * L2E;
        else     mc[n]   = (logf(w[n]) - 0.5f * ss) * L2E;
    }
}

// ---------------------------------------------------------------------------
// Main MFMA kernel (m97 structure): 128x128 tile, 4 waves 2x2, BK=32,
// global_load_lds width-16 staging, 16 mfma_f32_16x16x32_bf16 per wave per
// k-step, K=384 (12 steps). Epilogue: exp2(acc + xc + mc), width-16 shuffle
// reduce over cols, atomicAdd per row.
// ---------------------------------------------------------------------------
__global__ __launch_bounds__(256, 3) void gmm_mfma(
    const short* __restrict__ Acat, const short* __restrict__ Bcat,
    const float* __restrict__ xc, const float* __restrict__ mc,
    float* __restrict__ out)
{
    __shared__ __align__(16) short As[128 * 32];   // 8 KB
    __shared__ __align__(16) short Bs[128 * 32];   // 8 KB

    const int tid  = threadIdx.x;
    const int w    = tid >> 6, lane = tid & 63;
    const int wm   = w >> 1,   wn   = w & 1;
    const int quad = lane >> 4, col = lane & 15;
    const int m0 = blockIdx.x * 128, n0 = blockIdx.y * 128;

    // staging: each wave stages 32 A-rows and 32 B-rows per k-step,
    // 2 instructions each (16 rows x 64B = 1KB per instruction).
    const short* ga0 = Acat + (size_t)(m0 + w * 32 + (lane >> 2)) * 384 + (lane & 3) * 8;
    const short* ga1 = ga0 + (size_t)16 * 384;
    const short* gb0 = Bcat + (size_t)(n0 + w * 32 + (lane >> 2)) * 384 + (lane & 3) * 8;
    const short* gb1 = gb0 + (size_t)16 * 384;
    short* la0 = As + (w * 32) * 32;
    short* la1 = As + (w * 32 + 16) * 32;
    short* lb0 = Bs + (w * 32) * 32;
    short* lb1 = Bs + (w * 32 + 16) * 32;

    f32x4 acc[4][4];
    #pragma unroll
    for (int i = 0; i < 4; ++i)
        #pragma unroll
        for (int j = 0; j < 4; ++j)
            acc[i][j] = (f32x4){0.f, 0.f, 0.f, 0.f};

    for (int ks = 0; ks < 12; ++ks) {
        const int ko = ks * 32;
        async16(la0, ga0 + ko);
        async16(la1, ga1 + ko);
        async16(lb0, gb0 + ko);
        async16(lb1, gb1 + ko);
        __syncthreads();   // drains vmcnt (compiler-inserted) before LDS reads

        bf16x8 af[4];
        #pragma unroll
        for (int i = 0; i < 4; ++i)
            af[i] = *(const bf16x8*)(As + (wm * 64 + i * 16 + col) * 32 + quad * 8);
        #pragma unroll
        for (int j = 0; j < 4; ++j) {
            bf16x8 bfr = *(const bf16x8*)(Bs + (wn * 64 + j * 16 + col) * 32 + quad * 8);
            #pragma unroll
            for (int i = 0; i < 4; ++i)
                acc[i][j] = __builtin_amdgcn_mfma_f32_16x16x32_bf16(
                    af[i], bfr, acc[i][j], 0, 0, 0);
        }
        __syncthreads();
    }

    // epilogue: C/D layout col = lane&15, row = quad*4 + reg
    float mcv[4];
    #pragma unroll
    for (int j = 0; j < 4; ++j) mcv[j] = mc[n0 + wn * 64 + j * 16 + col];

    #pragma unroll
    for (int i = 0; i < 4; ++i) {
        float4 xcv = *(const float4*)(xc + m0 + wm * 64 + i * 16 + quad * 4);
        float xa[4] = {xcv.x, xcv.y, xcv.z, xcv.w};
        #pragma unroll
        for (int r = 0; r < 4; ++r) {
            float s = 0.f;
            #pragma unroll
            for (int j = 0; j < 4; ++j)
                s += __builtin_exp2f(acc[i][j][r] + xa[r] + mcv[j]);
            s += __shfl_xor(s, 1, 16);
            s += __shfl_xor(s, 2, 16);
            s += __shfl_xor(s, 4, 16);
            s += __shfl_xor(s, 8, 16);
            if (col == 0)
                atomicAdd(out + m0 + wm * 64 + i * 16 + quad * 4 + r, COEF * s);
        }
    }
}

// ===========================================================================
// Fallback fp32 path (round-1 kernels) — used only if ws_size is too small
// for the bf16 split buffers.
// ===========================================================================
__global__ __launch_bounds__(256) void gmm_prep(
    const float* __restrict__ x, const float* __restrict__ means,
    const float* __restrict__ w, float* __restrict__ xc, float* __restrict__ mc)
{
    int tid = blockIdx.x * 256 + threadIdx.x;
    if (tid < MM) {
        const float4* row = (const float4*)(x + (size_t)tid * DD);
        float ss = 0.f;
        #pragma unroll
        for (int i = 0; i < DD / 4; ++i) {
            float4 v = row[i];
            ss = fmaf(v.x, v.x, fmaf(v.y, v.y, fmaf(v.z, v.z, fmaf(v.w, v.w, ss))));
        }
        xc[tid] = -0.5f * ss * L2E;
    } else if (tid < MM + NN) {
        int n = tid - MM;
        const float4* row = (const float4*)(means + (size_t)n * DD);
        float ss = 0.f;
        #pragma unroll
        for (int i = 0; i < DD / 4; ++i) {
            float4 v = row[i];
            ss = fmaf(v.x, v.x, fmaf(v.y, v.y, fmaf(v.z, v.z, fmaf(v.w, v.w, ss))));
        }
        mc[n] = (logf(w[n]) - 0.5f * ss) * L2E;
    }
}

__global__ __launch_bounds__(256, 2) void gmm_main(
    const float* __restrict__ x, const float* __restrict__ means,
    const float* __restrict__ xc, const float* __restrict__ mc,
    float* __restrict__ out)
{
    __shared__ __align__(16) float Asm[128 * 128];
    __shared__ __align__(16) float Bsm[2][16 * 128];

    const int t   = threadIdx.x;
    const int tc  = t & 15;
    const int tr  = t >> 4;
    const int r0  = blockIdx.x * 128;
    const int nq0 = blockIdx.y * 2048;

    {
        float4 tmp[16];
        #pragma unroll
        for (int ii = 0; ii < 16; ++ii) {
            int idx = t + ii * 256;
            int r   = idx >> 5;
            int k0  = (idx & 31) << 2;
            tmp[ii] = *(const float4*)(x + (size_t)(r0 + r) * DD + k0);
        }
        #pragma unroll
        for (int ii = 0; ii < 16; ++ii) {
            int idx = t + ii * 256;
            int r   = idx >> 5;
            int k0  = (idx & 31) << 2;
            int rb  = r >> 3, rl = r & 7;
            float v[4] = {tmp[ii].x, tmp[ii].y, tmp[ii].z, tmp[ii].w};
            #pragma unroll
            for (int j = 0; j < 4; ++j) {
                int k = k0 + j;
                Asm[k * 128 + (((rb ^ (k & 15)) << 3) | rl)] = v[j];
            }
        }
    }

    float xcv[8];
    {
        float4 a = *(const float4*)(xc + r0 + tr * 8);
        float4 b = *(const float4*)(xc + r0 + tr * 8 + 4);
        xcv[0] = a.x; xcv[1] = a.y; xcv[2] = a.z; xcv[3] = a.w;
        xcv[4] = b.x; xcv[5] = b.y; xcv[6] = b.z; xcv[7] = b.w;
    }

    float rowAcc[8];
    #pragma unroll
    for (int i = 0; i < 8; ++i) rowAcc[i] = 0.f;

    for (int ntile = 0; ntile < 16; ++ntile) {
        const int nbase = nq0 + ntile * 128;

        float acc[8][8];
        #pragma unroll
        for (int i = 0; i < 8; ++i)
            #pragma unroll
            for (int j = 0; j < 8; ++j) acc[i][j] = 0.f;

        float4 ld[2];
        #pragma unroll
        for (int ii = 0; ii < 2; ++ii) {
            int flat = t + ii * 256;
            int nl   = flat >> 2;
            int kl   = (flat & 3) << 2;
            ld[ii] = *(const float4*)(means + (size_t)(nbase + nl) * DD + kl);
        }

        for (int ks = 0; ks < 8; ++ks) {
            const int buf = ks & 1;
            #pragma unroll
            for (int ii = 0; ii < 2; ++ii) {
                int flat = t + ii * 256;
                int nl   = flat >> 2;
                int k0   = (flat & 3) << 2;
                int nb   = nl >> 3, nll = nl & 7;
                float v[4] = {ld[ii].x, ld[ii].y, ld[ii].z, ld[ii].w};
                #pragma unroll
                for (int j = 0; j < 4; ++j) {
                    int kl = k0 + j;
                    Bsm[buf][kl * 128 + (((nb ^ kl) << 3) | nll)] = v[j];
                }
            }
            if (ks < 7) {
                #pragma unroll
                for (int ii = 0; ii < 2; ++ii) {
                    int flat = t + ii * 256;
                    int nl   = flat >> 2;
                    int kl   = (flat & 3) << 2;
                    ld[ii] = *(const float4*)(means + (size_t)(nbase + nl) * DD
                                              + (ks + 1) * 16 + kl);
                }
            }
            __syncthreads();

            #pragma unroll
            for (int kk = 0; kk < 16; ++kk) {
                const int k = ks * 16 + kk;
                const float* ap = &Asm[k * 128 + ((tr ^ kk) << 3)];
                float4 a0 = *(const float4*)ap;
                float4 a1 = *(const float4*)(ap + 4);
                const float* bp = &Bsm[buf][kk * 128 + ((tc ^ kk) << 3)];
                float4 b0 = *(const float4*)bp;
                float4 b1 = *(const float4*)(bp + 4);
                float av[8] = {a0.x, a0.y, a0.z, a0.w, a1.x, a1.y, a1.z, a1.w};
                float bv[8] = {b0.x, b0.y, b0.z, b0.w, b1.x, b1.y, b1.z, b1.w};
                #pragma unroll
                for (int i = 0; i < 8; ++i)
                    #pragma unroll
                    for (int j = 0; j < 8; ++j)
                        acc[i][j] = fmaf(av[i], bv[j], acc[i][j]);
            }
        }

        float mcv[8];
        {
            float4 a = *(const float4*)(mc + nbase + tc * 8);
            float4 b = *(const float4*)(mc + nbase + tc * 8 + 4);
            mcv[0] = a.x; mcv[1] = a.y; mcv[2] = a.z; mcv[3] = a.w;
            mcv[4] = b.x; mcv[5] = b.y; mcv[6] = b.z; mcv[7] = b.w;
        }
        #pragma unroll
        for (int i = 0; i < 8; ++i) {
            float s = 0.f;
            #pragma unroll
            for (int j = 0; j < 8; ++j) {
                float arg = fmaf(acc[i][j], L2E, xcv[i] + mcv[j]);
                s += __builtin_exp2f(arg);
            }
            rowAcc[i] += s;
        }
    }

    #pragma unroll
    for (int i = 0; i < 8; ++i) {
        float v = rowAcc[i];
        v += __shfl_xor(v, 1, 16);
        v += __shfl_xor(v, 2, 16);
        v += __shfl_xor(v, 4, 16);
        v += __shfl_xor(v, 8, 16);
        if (tc == 0) atomicAdd(out + r0 + tr * 8 + i, COEF * v);
    }
}

extern "C" void kernel_launch(void* const* d_in, const int* in_sizes, int n_in,
                              void* d_out, int out_size, void* d_ws, size_t ws_size,
                              hipStream_t stream) {
    const float* x     = (const float*)d_in[0];
    const float* means = (const float*)d_in[1];
    const float* w     = (const float*)d_in[2];
    float* out = (float*)d_out;

    const size_t needA = (size_t)MM * 384 * sizeof(short);   // 12.6 MB
    const size_t needB = (size_t)NN * 384 * sizeof(short);   //  6.3 MB
    const size_t need  = needA + needB + (size_t)MM * 4 + (size_t)NN * 4;

    hipMemsetAsync(out, 0, MM * sizeof(float), stream);

    if (ws_size >= need) {
        short* Acat = (short*)d_ws;
        short* Bcat = Acat + (size_t)MM * 384;
        float* xc   = (float*)(Bcat + (size_t)NN * 384);
        float* mc   = xc + MM;
        gmm_prep_bf16<<<(MM + NN) / 4, 256, 0, stream>>>(x, means, w, Acat, Bcat, xc, mc);
        gmm_mfma<<<dim3(MM / 128, NN / 128), 256, 0, stream>>>(Acat, Bcat, xc, mc, out);
    } else {
        float* xc = (float*)d_ws;
        float* mc = xc + MM;
        gmm_prep<<<(MM + NN + 255) / 256, 256, 0, stream>>>(x, means, w, xc, mc);
        gmm_main<<<dim3(MM / 128, 4), 256, 0, stream>>>(x, means, xc, mc, out);
    }
}